// Round 6
// baseline (37.454 us; speedup 1.0000x reference)
//
#include <hip/hip_runtime.h>
#include <math.h>

typedef float v2f __attribute__((ext_vector_type(2)));

constexpr int NW = 14;
constexpr int DIM = 1 << NW;      // 16384
constexpr int BATCH = 256;
constexpr int NT = 1024;          // 16 waves; 16 amps/thread as 8 v2f pairs

// XOR bank swizzle on float index; folds bits 5..8, 9..12, 13 into bits 1..4
// ONLY (bit 0 preserved -> P=0 pairs stay LDS-adjacent and 8B-aligned).
// XOR-linear: swz(a^b) = swz(a)^swz(b).
__device__ __host__ constexpr int swz(int i) {
    return i ^ (((i >> 5) & 15) << 1) ^ (((i >> 9) & 15) << 1) ^ (((i >> 13) & 1) << 1);
}

__device__ __forceinline__ float rfl(float x) {
    return __int_as_float(__builtin_amdgcn_readfirstlane(__float_as_int(x)));
}

// Scatter thread id t (10 bits) to global bit positions.
// Q0..Q5 = lane bits 0..5 (Q4 = permlane16 slot, Q5 = permlane32 slot),
// Q6..Q9 = wave bits.
template<int Q0,int Q1,int Q2,int Q3,int Q4,int Q5,int Q6,int Q7,int Q8,int Q9>
__device__ __forceinline__ int scat10(int t) {
    return ((t & 1) << Q0) | (((t >> 1) & 1) << Q1) | (((t >> 2) & 1) << Q2) |
           (((t >> 3) & 1) << Q3) | (((t >> 4) & 1) << Q4) | (((t >> 5) & 1) << Q5) |
           (((t >> 6) & 1) << Q6) | (((t >> 7) & 1) << Q7) | (((t >> 8) & 1) << Q8) |
           (((t >> 9) & 1) << Q9);
}

// ---------------------------------------------------------------------------
// Uniform packed gate: wire = slot bit JW, target = slot bit JT; packed dim
// (v2f halves) is always a spectator -> every line is one v_pk op.
template<int JW, int JT>
__device__ __forceinline__ void gate_u(v2f (&pr)[8], v2f (&pi)[8],
                                       float cy, float sy, float c1, float s1,
                                       float cx, float sx)
{
    constexpr int BW = 1 << JW, BT = 1 << JT, JF = 3 - JW - JT;
    #pragma unroll
    for (int m = 0; m < 2; ++m) {
        const int l00 = m << JF;
        const int iA = l00, iB = l00 | BW, iC = l00 | BT, iD = l00 | BW | BT;

        v2f a00r = pr[iA], a00i = pi[iA];
        v2f a10r = pr[iB], a10i = pi[iB];
        v2f a01r = pr[iC], a01i = pi[iC];
        v2f a11r = pr[iD], a11i = pi[iD];

        // RY (real) on wire bit
        v2f v0r = cy*a00r - sy*a10r, v0i = cy*a00i - sy*a10i;
        v2f v1r = sy*a00r + cy*a10r, v1i = sy*a00i + cy*a10i;
        v2f u0r = cy*a01r - sy*a11r, u0i = cy*a01i - sy*a11i;
        v2f u1r = sy*a01r + cy*a11r, u1i = sy*a01i + cy*a11i;

        // RZ phase on wire bit
        v2f b00r = c1*v0r + s1*v0i, b00i = c1*v0i - s1*v0r;
        v2f b10r = c1*v1r - s1*v1i, b10i = c1*v1i + s1*v1r;
        v2f b01r = c1*u0r + s1*u0i, b01i = c1*u0i - s1*u0r;
        v2f b11r = c1*u1r - s1*u1i, b11i = c1*u1i + s1*u1r;

        // CNOT(w->t) then RX(w)
        v2f o00r = cx*b00r + sx*b11i, o00i = cx*b00i - sx*b11r;
        v2f o10r = sx*b00i + cx*b11r, o10i = cx*b11i - sx*b00r;
        v2f o01r = cx*b01r + sx*b10i, o01i = cx*b01i - sx*b10r;
        v2f o11r = sx*b01i + cx*b10r, o11i = cx*b10i - sx*b01r;

        pr[iA] = o00r; pi[iA] = o00i;
        pr[iB] = o10r; pi[iB] = o10i;
        pr[iC] = o01r; pi[iC] = o01i;
        pr[iD] = o11r; pi[iD] = o11i;
    }
}

// ---------------------------------------------------------------------------
// Exchange slot bit J with lane bit 5 / lane bit 4 (proven R4/R5 pattern).
template<int J>
__device__ __forceinline__ void swap_l5(v2f (&pr)[8], v2f (&pi)[8]) {
    constexpr int jA = (J == 0) ? 1 : 0, jB = (J == 2) ? 1 : 2;
    #pragma unroll
    for (int m = 0; m < 4; ++m) {
        const int l0 = ((m & 1) << jA) | (((m >> 1) & 1) << jB);
        const int l1 = l0 | (1 << J);
        { float a=pr[l0].x, c=pr[l1].x; asm("s_nop 1\n\tv_permlane32_swap_b32 %0, %1":"+v"(a),"+v"(c)); pr[l0].x=a; pr[l1].x=c; }
        { float a=pr[l0].y, c=pr[l1].y; asm("s_nop 1\n\tv_permlane32_swap_b32 %0, %1":"+v"(a),"+v"(c)); pr[l0].y=a; pr[l1].y=c; }
        { float a=pi[l0].x, c=pi[l1].x; asm("s_nop 1\n\tv_permlane32_swap_b32 %0, %1":"+v"(a),"+v"(c)); pi[l0].x=a; pi[l1].x=c; }
        { float a=pi[l0].y, c=pi[l1].y; asm("s_nop 1\n\tv_permlane32_swap_b32 %0, %1":"+v"(a),"+v"(c)); pi[l0].y=a; pi[l1].y=c; }
    }
}

template<int J>
__device__ __forceinline__ void swap_l4(v2f (&pr)[8], v2f (&pi)[8]) {
    constexpr int jA = (J == 0) ? 1 : 0, jB = (J == 2) ? 1 : 2;
    #pragma unroll
    for (int m = 0; m < 4; ++m) {
        const int l0 = ((m & 1) << jA) | (((m >> 1) & 1) << jB);
        const int l1 = l0 | (1 << J);
        { float a=pr[l0].x, c=pr[l1].x; asm("s_nop 1\n\tv_permlane16_swap_b32 %0, %1":"+v"(a),"+v"(c)); pr[l0].x=a; pr[l1].x=c; }
        { float a=pr[l0].y, c=pr[l1].y; asm("s_nop 1\n\tv_permlane16_swap_b32 %0, %1":"+v"(a),"+v"(c)); pr[l0].y=a; pr[l1].y=c; }
        { float a=pi[l0].x, c=pi[l1].x; asm("s_nop 1\n\tv_permlane16_swap_b32 %0, %1":"+v"(a),"+v"(c)); pi[l0].x=a; pi[l1].x=c; }
        { float a=pi[l0].y, c=pi[l1].y; asm("s_nop 1\n\tv_permlane16_swap_b32 %0, %1":"+v"(a),"+v"(c)); pi[l0].y=a; pi[l1].y=c; }
    }
}

// ---------------------------------------------------------------------------
// LDS round trips. S0,S1,S2 = global positions of reg-index bits.
// P=0 phases: v2f <-> ds b64 directly (pairs adjacent, swizzle keeps bit 0).
template<int S0,int S1,int S2>
__device__ __forceinline__ void store64(float* re, float* im,
                                        const v2f (&pr)[8], const v2f (&pi)[8], int sb) {
    #pragma unroll
    for (int k = 0; k < 8; ++k) {
        const int c = swz(((k & 1) << S0) | (((k >> 1) & 1) << S1) | (((k >> 2) & 1) << S2));
        const int a = sb ^ c;
        *(v2f*)(re + a) = pr[k];
        *(v2f*)(im + a) = pi[k];
    }
}

template<int S0,int S1,int S2>
__device__ __forceinline__ void load64(const float* re, const float* im,
                                       v2f (&pr)[8], v2f (&pi)[8], int sb) {
    #pragma unroll
    for (int k = 0; k < 8; ++k) {
        const int c = swz(((k & 1) << S0) | (((k >> 1) & 1) << S1) | (((k >> 2) & 1) << S2));
        const int a = sb ^ c;
        pr[k] = *(const v2f*)(re + a);
        pi[k] = *(const v2f*)(im + a);
    }
}

// P=5 phases: halves differ in bit 5 -> 2x b32 per v2f (no movs needed).
template<int S0,int S1,int S2>
__device__ __forceinline__ void store32(float* re, float* im,
                                        const v2f (&pr)[8], const v2f (&pi)[8], int sb) {
    #pragma unroll
    for (int k = 0; k < 8; ++k) {
        const int cc = ((k & 1) << S0) | (((k >> 1) & 1) << S1) | (((k >> 2) & 1) << S2);
        const int a0 = sb ^ swz(cc);
        const int a1 = sb ^ swz(cc | 32);
        re[a0] = pr[k].x; re[a1] = pr[k].y;
        im[a0] = pi[k].x; im[a1] = pi[k].y;
    }
}

template<int S0,int S1,int S2>
__device__ __forceinline__ void load32(const float* re, const float* im,
                                       v2f (&pr)[8], v2f (&pi)[8], int sb) {
    #pragma unroll
    for (int k = 0; k < 8; ++k) {
        const int cc = ((k & 1) << S0) | (((k >> 1) & 1) << S1) | (((k >> 2) & 1) << S2);
        const int a0 = sb ^ swz(cc);
        const int a1 = sb ^ swz(cc | 32);
        pr[k].x = re[a0]; pr[k].y = re[a1];
        pi[k].x = im[a0]; pi[k].y = im[a1];
    }
}

__global__ __launch_bounds__(NT, 1) void qsim(const float* __restrict__ state,
                                              const float* __restrict__ params,
                                              const float* __restrict__ head_w,
                                              const float* __restrict__ head_b,
                                              float* __restrict__ out)
{
    __shared__ float re[DIM];           // 64 KiB
    __shared__ float im[DIM];           // 64 KiB
    __shared__ float2 csv[NW * 3 * 2];  // (cos,sin) of half-angles, 84 gates
    __shared__ float partial[NT / 64];

    const int t = threadIdx.x;
    const int b = blockIdx.x;

    v2f pr[8], pi[8];

    // ---- Start-P1 layout: k0->11,k1->12,k2->13; P->0;
    //      lanes t0->1,t1->2,t2->3,t3->4, L4->9, L5->10; waves t6..t9 -> 5,6,7,8.
    const float2* __restrict__ sp2 = (const float2*)(state + (size_t)b * DIM);
    const int tb1 = scat10<1,2,3,4,9,10,5,6,7,8>(t);
    #pragma unroll
    for (int k = 0; k < 8; ++k) {
        const int idx = tb1 | ((k & 1) << 11) | (((k >> 1) & 1) << 12) | (((k >> 2) & 1) << 13);
        const float2 v = sp2[idx >> 1];
        pr[k] = v2f{v.x, v.y};
        pi[k] = v2f{0.0f, 0.0f};
    }

    if (t < NW * 3 * 2) {
        float sv, cv;
        sincosf(params[t] * 0.5f, &sv, &cv);
        csv[t] = make_float2(cv, sv);
    }
    __syncthreads();

#define GU(JW, JT, G) do {                                              \
        float2 vy = csv[(G)*3+0], vz = csv[(G)*3+1], vx = csv[(G)*3+2]; \
        gate_u<JW, JT>(pr, pi, rfl(vy.x), rfl(vy.y), rfl(vz.x),         \
                       rfl(vz.y), rfl(vx.x), rfl(vx.y));                \
    } while (0)

    // ---- P1: gates (13,12),(12,11),(11,10),(10,9)  [L1 w0-3] ----
    GU(2, 1, 0);
    GU(1, 0, 1);
    swap_l5<2>(pr, pi);   // S2: 13 <-> L5: 10
    GU(0, 2, 2);
    swap_l4<1>(pr, pi);   // S1: 12 <-> L4: 9
    GU(2, 1, 3);
    // End-P1: k=[11,9,10]; L4->12, L5->13
    store64<11,9,10>(re, im, pr, pi, swz(scat10<1,2,3,4,12,13,5,6,7,8>(t)));
    __syncthreads();

    // ---- P2: gates (9,8),(8,7),(7,6),(6,5)  [L1 w4-7] ----
    // Start: k=[7,8,9]; lanes 1,2,3,4, L4->5, L5->6; waves 13,12,11,10.
    load64<7,8,9>(re, im, pr, pi, swz(scat10<1,2,3,4,5,6,13,12,11,10>(t)));
    GU(2, 1, 4);
    GU(1, 0, 5);
    swap_l5<2>(pr, pi);   // 9 <-> 6
    GU(0, 2, 6);
    swap_l4<1>(pr, pi);   // 8 <-> 5
    GU(2, 1, 7);
    // End-P2: k=[7,5,6]; L4->8, L5->9
    store64<7,5,6>(re, im, pr, pi, swz(scat10<1,2,3,4,8,9,13,12,11,10>(t)));
    __syncthreads();

    // ---- P3: gates (5,4),(4,3),(3,2),(2,1)  [L1 w8-11] ----
    // Start: k=[3,4,5]; lanes 13,6,7,8, L4->1, L5->2; waves 12,11,10,9.
    load64<3,4,5>(re, im, pr, pi, swz(scat10<13,6,7,8,1,2,12,11,10,9>(t)));
    GU(2, 1, 8);
    GU(1, 0, 9);
    swap_l5<2>(pr, pi);   // 5 <-> 2
    GU(0, 2, 10);
    swap_l4<1>(pr, pi);   // 4 <-> 1
    GU(2, 1, 11);
    // End-P3: k=[3,1,2]; L4->4, L5->5
    store64<3,1,2>(re, im, pr, pi, swz(scat10<13,6,7,8,4,5,12,11,10,9>(t)));
    __syncthreads();

    // ---- P4: gates (1,0),(0,13),(13,12),(12,11)  [L1 w12,13 + L2 w0,1], P=5 ----
    // Start: k=[13,0,1]; lanes 2,3,4,9, L4->11, L5->12; waves 10,8,7,6.
    load32<13,0,1>(re, im, pr, pi, swz(scat10<2,3,4,9,11,12,10,8,7,6>(t)));
    GU(2, 1, 12);
    GU(1, 0, 13);
    swap_l5<2>(pr, pi);   // 1 <-> 12
    GU(0, 2, 14);
    swap_l4<1>(pr, pi);   // 0 <-> 11
    GU(2, 1, 15);
    // End-P4: k=[13,11,12]; L4->0, L5->1
    store32<13,11,12>(re, im, pr, pi, swz(scat10<2,3,4,9,0,1,10,8,7,6>(t)));
    __syncthreads();

    // ---- P5: gates (11,10),(10,9),(9,8),(8,7)  [L2 w2-5] ----
    // Start: k=[9,10,11]; lanes 1,2,3,4, L4->7, L5->8; waves 13,12,6,5.
    load64<9,10,11>(re, im, pr, pi, swz(scat10<1,2,3,4,7,8,13,12,6,5>(t)));
    GU(2, 1, 16);
    GU(1, 0, 17);
    swap_l5<2>(pr, pi);   // 11 <-> 8
    GU(0, 2, 18);
    swap_l4<1>(pr, pi);   // 10 <-> 7
    GU(2, 1, 19);
    // End-P5: k=[9,7,8]; L4->10, L5->11
    store64<9,7,8>(re, im, pr, pi, swz(scat10<1,2,3,4,10,11,13,12,6,5>(t)));
    __syncthreads();

    // ---- P6: gates (7,6),(6,5),(5,4),(4,3)  [L2 w6-9] ----
    // Start: k=[5,6,7]; lanes 1,2,11,8, L4->3, L5->4; waves 13,12,10,9.
    load64<5,6,7>(re, im, pr, pi, swz(scat10<1,2,11,8,3,4,13,12,10,9>(t)));
    GU(2, 1, 20);
    GU(1, 0, 21);
    swap_l5<2>(pr, pi);   // 7 <-> 4
    GU(0, 2, 22);
    swap_l4<1>(pr, pi);   // 6 <-> 3
    GU(2, 1, 23);
    // End-P6: k=[5,3,4]; L4->6, L5->7
    store64<5,3,4>(re, im, pr, pi, swz(scat10<1,2,11,8,6,7,13,12,10,9>(t)));
    __syncthreads();

    // ---- P7: gates (3,2),(2,1),(1,0),(0,13)  [L2 w10-13], P=5; epilogue from regs ----
    // Start: k=[1,2,3]; lanes 9,10,11,12, L4->13, L5->0; waves 8,7,6,4.
    load32<1,2,3>(re, im, pr, pi, swz(scat10<9,10,11,12,13,0,8,7,6,4>(t)));
    GU(2, 1, 24);
    GU(1, 0, 25);
    swap_l5<2>(pr, pi);   // 3 <-> 0
    GU(0, 2, 26);
    swap_l4<1>(pr, pi);   // 2 <-> 13
    GU(2, 1, 27);
    // End-P7: k=[1,13,0]; P=5; lanes 9,10,11,12, L4->2, L5->3; waves 8,7,6,4.

    // ---- Epilogue: out[b] = sum_i |amp_i|^2 * g(i) + head_b ----
    // g(i) = sum_p hw[13-p]*(1-2*bit_p(i)).
    float hw[NW];
    #pragma unroll
    for (int w = 0; w < NW; ++w) hw[w] = head_w[w];

    float gbase = 0.0f;
    gbase += (t & 1)   ? -hw[4]  : hw[4];    // t0 -> bit 9
    gbase += (t & 2)   ? -hw[3]  : hw[3];    // t1 -> bit 10
    gbase += (t & 4)   ? -hw[2]  : hw[2];    // t2 -> bit 11
    gbase += (t & 8)   ? -hw[1]  : hw[1];    // t3 -> bit 12
    gbase += (t & 16)  ? -hw[11] : hw[11];   // t4 -> bit 2
    gbase += (t & 32)  ? -hw[10] : hw[10];   // t5 -> bit 3
    gbase += (t & 64)  ? -hw[5]  : hw[5];    // t6 -> bit 8
    gbase += (t & 128) ? -hw[6]  : hw[6];    // t7 -> bit 7
    gbase += (t & 256) ? -hw[7]  : hw[7];    // t8 -> bit 6
    gbase += (t & 512) ? -hw[9]  : hw[9];    // t9 -> bit 4

    v2f acc2 = {0.0f, 0.0f};
    #pragma unroll
    for (int k = 0; k < 8; ++k) {
        float g = gbase;
        g += (k & 1) ? -hw[12] : hw[12];     // k0 -> bit 1
        g += (k & 2) ? -hw[0]  : hw[0];      // k1 -> bit 13
        g += (k & 4) ? -hw[13] : hw[13];     // k2 -> bit 0
        v2f gv = {g + hw[8], g - hw[8]};     // P -> bit 5
        acc2 += (pr[k]*pr[k] + pi[k]*pi[k]) * gv;
    }
    float acc = acc2.x + acc2.y;

    #pragma unroll
    for (int off = 32; off > 0; off >>= 1) acc += __shfl_down(acc, off);
    if ((t & 63) == 0) partial[t >> 6] = acc;
    __syncthreads();
    if (t == 0) {
        float tot = 0.0f;
        #pragma unroll
        for (int k = 0; k < NT / 64; ++k) tot += partial[k];
        out[b] = tot + head_b[0];
    }
#undef GU
}

extern "C" void kernel_launch(void* const* d_in, const int* in_sizes, int n_in,
                              void* d_out, int out_size, void* d_ws, size_t ws_size,
                              hipStream_t stream) {
    const float* state  = (const float*)d_in[0];
    const float* params = (const float*)d_in[1];
    const float* head_w = (const float*)d_in[2];
    const float* head_b = (const float*)d_in[3];
    float* outp = (float*)d_out;
    qsim<<<BATCH, NT, 0, stream>>>(state, params, head_w, head_b, outp);
}